// Round 1
// baseline (43.626 us; speedup 1.0000x reference)
//
#include <hip/hip_runtime.h>

// QLIF spike forward: x [B=32, T=8, C=128, H=32, W=32] f32 -> spikes same shape.
// Recurrence per (b,c,h,w): mem = mem*0.5 + x_t; spike = mem > 1; mem = spike?0:mem;
// mem = clip(rint(mem+30), 0, 31) - 30.
// Memory-bound: 268 MB total traffic, roofline ~43 us at 6.3 TB/s.

typedef float f4 __attribute__((ext_vector_type(4)));

constexpr int   T_STEPS   = 8;
constexpr int   VEC_PER_T = 128 * 32 * 32 / 4;  // C*H*W / 4 = 32768 (power of 2)

__global__ __launch_bounds__(256) void qlif_kernel(const f4* __restrict__ x,
                                                   f4* __restrict__ out) {
    int idx = blockIdx.x * blockDim.x + threadIdx.x;   // [0, B*VEC_PER_T)
    int b   = idx >> 15;                               // idx / VEC_PER_T
    int pos = idx & (VEC_PER_T - 1);                   // idx % VEC_PER_T

    size_t base = (size_t)b * (T_STEPS * VEC_PER_T) + pos;
    const f4* xp = x + base;
    f4*       op = out + base;

    f4 m = {0.f, 0.f, 0.f, 0.f};

#pragma unroll
    for (int t = 0; t < T_STEPS; ++t) {
        f4 v = xp[(size_t)t * VEC_PER_T];
        f4 s;
#pragma unroll
        for (int k = 0; k < 4; ++k) {
            // mem = mem*tau + x  (tau=0.5: exact pow2 multiply, single rounding on add)
            float mm = m[k] * 0.5f + v[k];
            // spike = heaviside(mem - 1)
            bool fired = (mm > 1.0f);
            s[k] = fired ? 1.0f : 0.0f;
            // soft reset
            mm = fired ? 0.0f : mm;
            // quantize to {-30 + i : i=0..31}, round-half-even like np.round
            float q = rintf(mm + 30.0f);
            q = fminf(fmaxf(q, 0.0f), 31.0f);
            m[k] = q - 30.0f;
        }
        op[(size_t)t * VEC_PER_T] = s;
    }
}

extern "C" void kernel_launch(void* const* d_in, const int* in_sizes, int n_in,
                              void* d_out, int out_size, void* d_ws, size_t ws_size,
                              hipStream_t stream) {
    const f4* x   = (const f4*)d_in[0];
    f4*       out = (f4*)d_out;

    // total independent vector positions = B * C*H*W/4 = total_elems / (T*4)
    int total_threads = in_sizes[0] / (T_STEPS * 4);   // 1,048,576
    int block = 256;
    int grid  = (total_threads + block - 1) / block;   // 4096

    qlif_kernel<<<grid, block, 0, stream>>>(x, out);
}